// Round 19
// baseline (238.953 us; speedup 1.0000x reference)
//
#include <hip/hip_runtime.h>

#define NB 8
#define NNODE 2048
#define NE 32768
#define NG 4
#define NH 64
#define NMLP 128

typedef _Float16 f16x8 __attribute__((ext_vector_type(8)));
typedef _Float16 f16x4 __attribute__((ext_vector_type(4)));
typedef float f32x4 __attribute__((ext_vector_type(4)));

// ---------------- persistent device scratch ----------------------------------
__device__ __align__(16) float g_bc[2*NG*64];        // folded layer-1 bias
__device__ __align__(16) float g_q1[64];             // se_w @ nu1_w[0:64]
__device__ __align__(16) float g_b1f[64];            // se_b @ nu1_w[0:64] + nu1_b
__device__ __align__(16) _Float16 g_em16[(size_t)NE*NB*64]; // edge messages, CSR-ordered (fp16)
__device__ __align__(16) float g_psum[NB*NMLP];
// split-fp16 fragment tables (filled once by k_setup block 1)
__device__ f16x8 g_w1hi[2*NG*4*64];       // edge layer-1 folded W frags [p][g][nt][lane] (K=32)
__device__ f16x8 g_w1lo[2*NG*4*64];
__device__ f16x4 g_w2hi16[2*NG*4*4*64];   // edge layer-2 W frags [p][g][nto][ntk][lane] (K=16)
__device__ f16x4 g_w2lo16[2*NG*4*4*64];
__device__ f16x8 g_wn1hi[4*2*64];         // node nu1_w[64:] frags [nt][kb][lane] (K=32)
__device__ f16x8 g_wn1lo[4*2*64];
__device__ f16x8 g_wn2hi[4*2*64];         // node nu2_w frags
__device__ f16x8 g_wn2lo[4*2*64];
__device__ f16x8 g_wp1hi[8*2*64];         // node p1_w frags [nt8][kb][lane]
__device__ f16x8 g_wp1lo[8*2*64];
__device__ int g_elist[NG*NE];
__device__ int g_ecnt[NG];
__device__ int g_bstart[5];
__device__ int g_ncnt[NNODE];
__device__ int g_noff[NNODE];
__device__ int g_csrpos[NE];              // inverse CSR map: edge -> position

__device__ __forceinline__ float lrelu(float x){ return fmaxf(x, 0.01f*x); }

// ---------------- setup: block 0 = prep (sort/CSR), block 1 = fold+frag ------
__global__ __launch_bounds__(1024) void k_setup(
    const int* __restrict__ uc, const int* __restrict__ idx2,
    const float* __restrict__ se_w, const float* __restrict__ se_b,
    const float* __restrict__ ee_w, const float* __restrict__ ee_b,
    const float* __restrict__ m1a_w, const float* __restrict__ m1a_b,
    const float* __restrict__ m2a_w, const float* __restrict__ m2a_b,
    const float* __restrict__ nu1_w, const float* __restrict__ nu1_b,
    const float* __restrict__ m1b_w, const float* __restrict__ m2b_w,
    const float* __restrict__ nu2_w, const float* __restrict__ p1_w) {
  int t = threadIdx.x;
  if (blockIdx.x == 0) {
    // =================== PREP ===================
    __shared__ unsigned long long sgs[16];
    __shared__ int sws[16];
    __shared__ int sbins[NNODE];
    int lane = t & 63, wv = t >> 6;
    g_psum[t] = 0.f;                      // NB*NMLP == 1024

    int ucr[32], ixr[32];
    #pragma unroll
    for (int j=0;j<32;j++) ucr[j] = uc[j*1024 + t];
    #pragma unroll
    for (int j=0;j<32;j++) ixr[j] = idx2[j*1024 + t];

    // ---- bucket edges by group: packed u64 counts, block scan ----
    unsigned long long cnt = 0;
    #pragma unroll
    for (int j=0;j<32;j++) cnt += 1ULL << (ucr[j]*16);
    unsigned long long inc = cnt;
    #pragma unroll
    for (int d=1; d<64; d<<=1){
      unsigned long long v = __shfl_up(inc, d, 64);
      if (lane >= d) inc += v;
    }
    if (lane == 63) sgs[wv] = inc;
    __syncthreads();
    if (t < 16){
      unsigned long long w = sgs[t];
      #pragma unroll
      for (int d=1; d<16; d<<=1){
        unsigned long long v = __shfl_up(w, d, 64);
        if (t >= d) w += v;
      }
      sgs[t] = w;
    }
    __syncthreads();
    unsigned long long tot  = sgs[15];
    unsigned long long excl = inc - cnt + (wv ? sgs[wv-1] : 0);
    int tg0 = (int)(tot & 0xFFFF),        tg1 = (int)((tot>>16) & 0xFFFF),
        tg2 = (int)((tot>>32) & 0xFFFF),  tg3 = (int)((tot>>48) & 0xFFFF);
    // group-relative positions (g_elist is segmented by g*NE) — r12 fix
    int c0 = (int)(excl & 0xFFFF);
    int c1 = (int)((excl>>16) & 0xFFFF);
    int c2 = (int)((excl>>32) & 0xFFFF);
    int c3 = (int)((excl>>48) & 0xFFFF);
    #pragma unroll
    for (int j=0;j<32;j++){
      int e = j*1024 + t, g = ucr[j], pos;
      if      (g==0) pos = c0++;
      else if (g==1) pos = c1++;
      else if (g==2) pos = c2++;
      else           pos = c3++;
      g_elist[g*NE + pos] = e;
    }
    if (t == 0){
      g_ecnt[0]=tg0; g_ecnt[1]=tg1; g_ecnt[2]=tg2; g_ecnt[3]=tg3;
      int b1 = (tg0+7)/8, b2 = b1+(tg1+7)/8, b3 = b2+(tg2+7)/8, b4 = b3+(tg3+7)/8;
      g_bstart[0]=0; g_bstart[1]=b1; g_bstart[2]=b2; g_bstart[3]=b3; g_bstart[4]=b4;
    }

    // ---- node CSR offsets + inverse map (edge -> position) ----
    sbins[t] = 0; sbins[t+1024] = 0;
    __syncthreads();
    #pragma unroll
    for (int j=0;j<32;j++) atomicAdd(&sbins[ixr[j]], 1);
    __syncthreads();
    int b0v = sbins[2*t], b1v = sbins[2*t+1];
    int s = b0v + b1v;
    int insc = s;
    #pragma unroll
    for (int d=1; d<64; d<<=1){
      int v = __shfl_up(insc, d, 64);
      if (lane >= d) insc += v;
    }
    if (lane == 63) sws[wv] = insc;
    __syncthreads();
    if (t < 16){
      int w = sws[t];
      #pragma unroll
      for (int d=1; d<16; d<<=1){
        int v = __shfl_up(w, d, 64);
        if (t >= d) w += v;
      }
      sws[t] = w;
    }
    __syncthreads();
    int ex = insc - s + (wv ? sws[wv-1] : 0);
    g_ncnt[2*t] = b0v; g_ncnt[2*t+1] = b1v;
    g_noff[2*t] = ex;  g_noff[2*t+1] = ex + b0v;
    __syncthreads();
    sbins[2*t] = ex; sbins[2*t+1] = ex + b0v;
    __syncthreads();
    #pragma unroll
    for (int j=0;j<32;j++){
      int pos = atomicAdd(&sbins[ixr[j]], 1);
      g_csrpos[j*1024 + t] = pos;
    }
  } else {
    // =================== FOLD + FRAGMENT TABLES ===================
    __shared__ float sfold[2*NG*12*64];   // 24 KB
    if (t < 512) {
      int p = t>>8, g = (t>>6)&3, j = t&63;
      const float* ma = (p ? m2a_w : m1a_w) + g*160*64;
      const float* mb = (p ? m2a_b : m1a_b) + g*64;
      float* W = sfold + (p*NG+g)*12*64;
      float a0=0.f, a1=0.f, bc=0.f;
      for (int k=0;k<64;k++){
        float sw = se_w[k], sb = se_b[k];
        float w0 = ma[k*64+j], w1 = ma[(64+k)*64+j];
        a0 += sw*w0; a1 += sw*w1; bc += sb*(w0+w1);
      }
      W[0*64+j]=a0; W[1*64+j]=a1;
      for (int c=0;c<10;c++){
        float pc=0.f;
        for (int u=0;u<32;u++) pc += ee_w[c*32+u]*ma[(128+u)*64+j];
        W[(2+c)*64+j]=pc;
      }
      for (int u=0;u<32;u++) bc += ee_b[u]*ma[(128+u)*64+j];
      g_bc[(p*NG+g)*64+j] = bc + mb[j];
    } else if (t < 576) {
      int j = t - 512;
      float q=0.f, bf=0.f;
      for (int k=0;k<64;k++){ float w = nu1_w[k*64+j]; q += se_w[k]*w; bf += se_b[k]*w; }
      g_q1[j]=q; g_b1f[j]=bf + nu1_b[j];
    }
    __syncthreads();

    for (int i = t; i < 12288; i += 1024) {
      if (i < 8192) {               // edge W2 K16 frags
        int lane = i & 63, ntk = (i>>6)&3, nto = (i>>8)&3, g = (i>>10)&3, p = (i>>12)&1;
        int l15 = lane & 15, lg = lane >> 4;
        const float* W2g = (p ? m2b_w : m1b_w) + g*64*64;
        int n = nto*16 + l15;
        f16x4 h4, l4;
        #pragma unroll
        for (int j=0;j<4;j++){
          float w = W2g[(ntk*16 + lg*4 + j)*64 + n];
          _Float16 hh = (_Float16)w;
          h4[j] = hh; l4[j] = (_Float16)(w - (float)hh);
        }
        g_w2hi16[i] = h4; g_w2lo16[i] = l4;
      } else if (i < 10240) {       // edge W1 K32 frags (2048)
        int k2 = i - 8192;
        int lane = k2 & 63, nt = (k2>>6)&3, g = (k2>>8)&3, p = (k2>>10)&1;
        int l15 = lane & 15, lg = lane >> 4;
        const float* Wf = sfold + (p*NG+g)*12*64;
        int c = nt*16 + l15;
        f16x8 h8, l8;
        #pragma unroll
        for (int j=0;j<8;j++){
          int k = lg*8 + j;
          float w = (k < 12) ? Wf[k*64 + c] : 0.f;
          _Float16 hh = (_Float16)w;
          h8[j] = hh; l8[j] = (_Float16)(w - (float)hh);
        }
        g_w1hi[k2] = h8; g_w1lo[k2] = l8;
      } else if (i < 10752) {       // node nu1_w[64:] frags
        int k2 = i - 10240;
        int lane = k2 & 63, kb = (k2>>6)&1, nt = (k2>>7)&3;
        int l15 = lane & 15, lg = lane >> 4;
        int c = nt*16 + l15;
        f16x8 h8, l8;
        #pragma unroll
        for (int j=0;j<8;j++){
          float w = nu1_w[(64 + kb*32 + lg*8 + j)*64 + c];
          _Float16 hh = (_Float16)w;
          h8[j] = hh; l8[j] = (_Float16)(w - (float)hh);
        }
        g_wn1hi[k2] = h8; g_wn1lo[k2] = l8;
      } else if (i < 11264) {       // node nu2_w frags
        int k2 = i - 10752;
        int lane = k2 & 63, kb = (k2>>6)&1, nt = (k2>>7)&3;
        int l15 = lane & 15, lg = lane >> 4;
        int c = nt*16 + l15;
        f16x8 h8, l8;
        #pragma unroll
        for (int j=0;j<8;j++){
          float w = nu2_w[(kb*32 + lg*8 + j)*64 + c];
          _Float16 hh = (_Float16)w;
          h8[j] = hh; l8[j] = (_Float16)(w - (float)hh);
        }
        g_wn2hi[k2] = h8; g_wn2lo[k2] = l8;
      } else {                      // node p1_w frags (8 nt)
        int k2 = i - 11264;
        int lane = k2 & 63, kb = (k2>>6)&1, nt = (k2>>7)&7;
        int l15 = lane & 15, lg = lane >> 4;
        int c = nt*16 + l15;
        f16x8 h8, l8;
        #pragma unroll
        for (int j=0;j<8;j++){
          float w = p1_w[(kb*32 + lg*8 + j)*128 + c];
          _Float16 hh = (_Float16)w;
          h8[j] = hh; l8[j] = (_Float16)(w - (float)hh);
        }
        g_wp1hi[k2] = h8; g_wp1lo[k2] = l8;
      }
    }
  }
}

// ---------------- edge kernel: r16 verbatim (best measured: ~45us) -----------
__global__ __launch_bounds__(128) void k_edge(
    const float* __restrict__ sites, const float* __restrict__ bonds,
    const int* __restrict__ idx1, const int* __restrict__ idx2,
    const float* __restrict__ m1b_b, const float* __restrict__ m2b_b,
    const float* __restrict__ att1_w, const float* __restrict__ att1_b,
    const float* __restrict__ att2_w, const float* __restrict__ att2_b) {
  int bid = blockIdx.x;
  if (bid >= g_bstart[4]) return;
  int g;
  if      (bid < g_bstart[1]) g = 0;
  else if (bid < g_bstart[2]) g = 1;
  else if (bid < g_bstart[3]) g = 2;
  else                        g = 3;
  int cnt = g_ecnt[g];
  int e8 = (bid - g_bstart[g]) * 8;

  __shared__ __align__(16) float fls[64*12];
  __shared__ int sidx[64];

  int t = threadIdx.x;
  int l = t & 63;
  int wv = t >> 6;
  int l15 = l & 15;
  int lg  = l >> 4;

  if (t < 64) {
    int r = t, ei = r>>3, b = r&7;
    int eslot = e8 + ei;
    bool valid = eslot < cnt;
    int e = g_elist[g*NE + (valid ? eslot : e8)];
    int i1 = idx1[e], i2 = idx2[e];
    float d = bonds[b*NE + e];
    fls[r*12+0] = sites[b*NNODE + i1];
    fls[r*12+1] = sites[b*NNODE + i2];
    sidx[r] = valid ? (g_csrpos[e]*NB + b)*64 : -1;   // CSR-ordered destination
    #pragma unroll
    for (int c=0;c<10;c++){
      float dd = d - c*(10.f/9.f);
      fls[r*12+2+c] = __expf(-dd*dd);
    }
  }
  __syncthreads();

  // feature fragments (MFMA B operand), fp16-hi only: col r=l15, k=lg*8+jj
  f16x8 fhi[2];
  #pragma unroll
  for (int mt=0;mt<2;mt++){
    f16x8 h8;
    #pragma unroll
    for (int j=0;j<8;j++) h8[j]=(_Float16)0;
    int R = wv*32 + mt*16 + l15;
    if (lg == 0){
      float4 f0 = *(const float4*)&fls[R*12];
      float4 f1 = *(const float4*)&fls[R*12+4];
      h8[0]=(_Float16)f0.x; h8[1]=(_Float16)f0.y;
      h8[2]=(_Float16)f0.z; h8[3]=(_Float16)f0.w;
      h8[4]=(_Float16)f1.x; h8[5]=(_Float16)f1.y;
      h8[6]=(_Float16)f1.z; h8[7]=(_Float16)f1.w;
    } else if (lg == 1){
      float4 f2 = *(const float4*)&fls[R*12+8];
      h8[0]=(_Float16)f2.x; h8[1]=(_Float16)f2.y;
      h8[2]=(_Float16)f2.z; h8[3]=(_Float16)f2.w;
    }
    fhi[mt]=h8;
  }

  float comb[2][4][4];
  #pragma unroll
  for (int mt=0;mt<2;mt++)
    #pragma unroll
    for (int nt=0;nt<4;nt++)
      #pragma unroll
      for (int r=0;r<4;r++) comb[mt][nt][r] = 0.f;

  #pragma unroll
  for (int p=0;p<2;p++){
    const float* b2g = (p ? m2b_b : m1b_b) + g*64;
    int pg = p*NG + g;

    // ---- layer 1: C1 = mfma(W1, feat) = h^T — lands in K=16 A-frag layout
    f16x4 ah[4][2];   // [ntk][mt]
    #pragma unroll
    for (int nt=0;nt<4;nt++){
      int b1 = (pg*4 + nt)*64 + l;
      f16x8 w1h = g_w1hi[b1], w1l = g_w1lo[b1];
      float4 bc4 = *(const float4*)&g_bc[pg*64 + nt*16 + lg*4];
      #pragma unroll
      for (int mt=0;mt<2;mt++){
        f32x4 a = {bc4.x, bc4.y, bc4.z, bc4.w};
        a = __builtin_amdgcn_mfma_f32_16x16x32_f16(w1h, fhi[mt], a, 0,0,0);
        a = __builtin_amdgcn_mfma_f32_16x16x32_f16(w1l, fhi[mt], a, 0,0,0);
        f16x4 h4;
        #pragma unroll
        for (int r=0;r<4;r++) h4[r] = (_Float16)lrelu(a[r]);
        ah[nt][mt] = h4;
      }
    }

    // ---- layer 2: out[mt][nto] via K=16 MFMA over 4 ntk tiles
    f32x4 accp[2][4];
    #pragma unroll
    for (int nto=0;nto<4;nto++){
      float bias = b2g[nto*16 + l15];
      f32x4 a0v = {bias, bias, bias, bias};
      f32x4 a1v = {bias, bias, bias, bias};
      #pragma unroll
      for (int ntk=0;ntk<4;ntk++){
        int bi = (((pg*4 + nto)*4) + ntk)*64 + l;
        f16x4 bh = g_w2hi16[bi], bl = g_w2lo16[bi];
        a0v = __builtin_amdgcn_mfma_f32_16x16x16f16(ah[ntk][0], bh, a0v, 0,0,0);
        a0v = __builtin_amdgcn_mfma_f32_16x16x16f16(ah[ntk][0], bl, a0v, 0,0,0);
        a1v = __builtin_amdgcn_mfma_f32_16x16x16f16(ah[ntk][1], bh, a1v, 0,0,0);
        a1v = __builtin_amdgcn_mfma_f32_16x16x16f16(ah[ntk][1], bl, a1v, 0,0,0);
      }
      accp[0][nto] = a0v; accp[1][nto] = a1v;
    }

    // ---- per-path epilogue: leaky -> attention gate -> accumulate into comb
    float ab = p ? att2_b[0] : att1_b[0];
    const float* aw = p ? att2_w : att1_w;
    #pragma unroll
    for (int mt=0;mt<2;mt++){
      float o[4][4];
      float pa[4] = {0.f,0.f,0.f,0.f};
      #pragma unroll
      for (int nt=0;nt<4;nt++){
        float w = aw[nt*16 + l15];
        #pragma unroll
        for (int r=0;r<4;r++){
          float ov = lrelu(accp[mt][nt][r]);
          o[nt][r] = ov;
          pa[r] += ov * w;
        }
      }
      #pragma unroll
      for (int r=0;r<4;r++){
        float s = pa[r];
        s += __shfl_xor(s, 1, 64);
        s += __shfl_xor(s, 2, 64);
        s += __shfl_xor(s, 4, 64);
        s += __shfl_xor(s, 8, 64);
        float sg = 1.f/(1.f + __expf(-(s + ab)));
        #pragma unroll
        for (int nt=0;nt<4;nt++) comb[mt][nt][r] += sg * o[nt][r];
      }
    }
  }

  // store combined messages as fp16 (CSR-ordered rows)
  #pragma unroll
  for (int mt=0;mt<2;mt++){
    #pragma unroll
    for (int r=0;r<4;r++){
      int R = wv*32 + mt*16 + lg*4 + r;
      int sb = sidx[R];
      if (sb >= 0){
        #pragma unroll
        for (int nt=0;nt<4;nt++) g_em16[sb + nt*16 + l15] = (_Float16)comb[mt][nt][r];
      }
    }
  }
}

// ---------------- node kernel: fused gather + 3 chained MFMA GEMMs -----------
// r19: gather fused in. Each wave gathers its own 32 node-rows (batch b) from
// g_em16 (CSR-sequential, same summation order as old k_gather -> bit-identical)
// into swizzled hA, then reads its A-frags back (wave-private, no barrier).
// Deletes g_msg round-trip (8MB traffic) + one launch.
__global__ __launch_bounds__(128) void k_node(
    const float* __restrict__ sites,
    const float* __restrict__ se_w, const float* __restrict__ se_b,
    const float* __restrict__ nu2_b, const float* __restrict__ p1_b) {
  __shared__ __align__(16) float hA[64*64];
  __shared__ float xs[64];
  int t = threadIdx.x;
  int l = t & 63;
  int wv = t >> 6;
  int l15 = l & 15;
  int lg  = l >> 4;
  int swzR = l15 << 2;
  int b = blockIdx.x >> 5;
  int nbase = (blockIdx.x & 31) * 64;
  int wb = wv*32;

  if (t < 64) xs[t] = sites[b*NNODE + nbase + t];

  // phase 0: gather this wave's 32 node-rows into swizzled hA
  for (int k=0;k<32;k++){
    int rr = wb + k;
    int n = nbase + rr;
    int off = g_noff[n], deg = g_ncnt[n];
    float acc = 0.f;
    for (int i=0;i<deg;i++)
      acc += (float)g_em16[(size_t)((off+i)*NB + b)*64 + l];
    hA[rr*64 + (l ^ ((rr&15)<<2))] = acc;
  }
  __syncthreads();   // covers xs (cross-wave); hA rows are wave-private

  // GEMM1 A-frags from swizzled hA: row=l15(+wb+mt*16), k=kb*32+lg*8+j
  f16x8 ahi[2][2], alo[2][2];
  #pragma unroll
  for (int mt=0;mt<2;mt++){
    int R = wb + mt*16 + l15;
    #pragma unroll
    for (int kb=0;kb<2;kb++){
      int k0 = kb*32 + lg*8;
      const float4 f0 = *(const float4*)&hA[R*64 + ((k0    ) ^ swzR)];
      const float4 f1 = *(const float4*)&hA[R*64 + ((k0 + 4) ^ swzR)];
      f16x8 hi8, lo8;
      float v0;
      v0=f0.x; hi8[0]=(_Float16)v0; lo8[0]=(_Float16)(v0-(float)hi8[0]);
      v0=f0.y; hi8[1]=(_Float16)v0; lo8[1]=(_Float16)(v0-(float)hi8[1]);
      v0=f0.z; hi8[2]=(_Float16)v0; lo8[2]=(_Float16)(v0-(float)hi8[2]);
      v0=f0.w; hi8[3]=(_Float16)v0; lo8[3]=(_Float16)(v0-(float)hi8[3]);
      v0=f1.x; hi8[4]=(_Float16)v0; lo8[4]=(_Float16)(v0-(float)hi8[4]);
      v0=f1.y; hi8[5]=(_Float16)v0; lo8[5]=(_Float16)(v0-(float)hi8[5]);
      v0=f1.z; hi8[6]=(_Float16)v0; lo8[6]=(_Float16)(v0-(float)hi8[6]);
      v0=f1.w; hi8[7]=(_Float16)v0; lo8[7]=(_Float16)(v0-(float)hi8[7]);
      ahi[mt][kb]=hi8; alo[mt][kb]=lo8;
    }
  }

  // GEMM1: h1 = lrelu(x*q1 + msg @ nu1_w[64:] + b1f) -> swizzled LDS
  #pragma unroll
  for (int nt=0;nt<4;nt++){
    f16x8 wh0 = g_wn1hi[(nt*2+0)*64 + l], wl0 = g_wn1lo[(nt*2+0)*64 + l];
    f16x8 wh1 = g_wn1hi[(nt*2+1)*64 + l], wl1 = g_wn1lo[(nt*2+1)*64 + l];
    int c = nt*16 + l15;
    float q = g_q1[c], bf = g_b1f[c];
    #pragma unroll
    for (int mt=0;mt<2;mt++){
      f32x4 a;
      #pragma unroll
      for (int r=0;r<4;r++){ int R = wb + mt*16 + lg*4 + r; a[r] = xs[R]*q + bf; }
      a = __builtin_amdgcn_mfma_f32_16x16x32_f16(ahi[mt][0], wh0, a, 0,0,0);
      a = __builtin_amdgcn_mfma_f32_16x16x32_f16(ahi[mt][1], wh1, a, 0,0,0);
      a = __builtin_amdgcn_mfma_f32_16x16x32_f16(ahi[mt][0], wl0, a, 0,0,0);
      a = __builtin_amdgcn_mfma_f32_16x16x32_f16(ahi[mt][1], wl1, a, 0,0,0);
      a = __builtin_amdgcn_mfma_f32_16x16x32_f16(alo[mt][0], wh0, a, 0,0,0);
      a = __builtin_amdgcn_mfma_f32_16x16x32_f16(alo[mt][1], wh1, a, 0,0,0);
      #pragma unroll
      for (int r=0;r<4;r++){
        int R = wb + mt*16 + lg*4 + r;
        hA[R*64 + (c ^ ((R&15)<<2))] = lrelu(a[r]);
      }
    }
  }

  // read h1 back (wave-private)
  #pragma unroll
  for (int mt=0;mt<2;mt++){
    int R = wb + mt*16 + l15;
    #pragma unroll
    for (int kb=0;kb<2;kb++){
      int k0 = kb*32 + lg*8;
      const float4 f0 = *(const float4*)&hA[R*64 + ((k0    ) ^ swzR)];
      const float4 f1 = *(const float4*)&hA[R*64 + ((k0 + 4) ^ swzR)];
      f16x8 hi8, lo8;
      float v0;
      v0=f0.x; hi8[0]=(_Float16)v0; lo8[0]=(_Float16)(v0-(float)hi8[0]);
      v0=f0.y; hi8[1]=(_Float16)v0; lo8[1]=(_Float16)(v0-(float)hi8[1]);
      v0=f0.z; hi8[2]=(_Float16)v0; lo8[2]=(_Float16)(v0-(float)hi8[2]);
      v0=f0.w; hi8[3]=(_Float16)v0; lo8[3]=(_Float16)(v0-(float)hi8[3]);
      v0=f1.x; hi8[4]=(_Float16)v0; lo8[4]=(_Float16)(v0-(float)hi8[4]);
      v0=f1.y; hi8[5]=(_Float16)v0; lo8[5]=(_Float16)(v0-(float)hi8[5]);
      v0=f1.z; hi8[6]=(_Float16)v0; lo8[6]=(_Float16)(v0-(float)hi8[6]);
      v0=f1.w; hi8[7]=(_Float16)v0; lo8[7]=(_Float16)(v0-(float)hi8[7]);
      ahi[mt][kb]=hi8; alo[mt][kb]=lo8;
    }
  }

  // GEMM2: s_new = x*se_w + se_b + lrelu(h1 @ nu2_w + nu2_b) -> swizzled LDS
  #pragma unroll
  for (int nt=0;nt<4;nt++){
    f16x8 wh0 = g_wn2hi[(nt*2+0)*64 + l], wl0 = g_wn2lo[(nt*2+0)*64 + l];
    f16x8 wh1 = g_wn2hi[(nt*2+1)*64 + l], wl1 = g_wn2lo[(nt*2+1)*64 + l];
    int c = nt*16 + l15;
    float b2 = nu2_b[c], sw = se_w[c], sb2 = se_b[c];
    #pragma unroll
    for (int mt=0;mt<2;mt++){
      f32x4 a = {b2, b2, b2, b2};
      a = __builtin_amdgcn_mfma_f32_16x16x32_f16(ahi[mt][0], wh0, a, 0,0,0);
      a = __builtin_amdgcn_mfma_f32_16x16x32_f16(ahi[mt][1], wh1, a, 0,0,0);
      a = __builtin_amdgcn_mfma_f32_16x16x32_f16(ahi[mt][0], wl0, a, 0,0,0);
      a = __builtin_amdgcn_mfma_f32_16x16x32_f16(ahi[mt][1], wl1, a, 0,0,0);
      a = __builtin_amdgcn_mfma_f32_16x16x32_f16(alo[mt][0], wh0, a, 0,0,0);
      a = __builtin_amdgcn_mfma_f32_16x16x32_f16(alo[mt][1], wh1, a, 0,0,0);
      #pragma unroll
      for (int r=0;r<4;r++){
        int R = wb + mt*16 + lg*4 + r;
        hA[R*64 + (c ^ ((R&15)<<2))] = xs[R]*sw + sb2 + lrelu(a[r]);
      }
    }
  }

  // read s_new back (wave-private)
  #pragma unroll
  for (int mt=0;mt<2;mt++){
    int R = wb + mt*16 + l15;
    #pragma unroll
    for (int kb=0;kb<2;kb++){
      int k0 = kb*32 + lg*8;
      const float4 f0 = *(const float4*)&hA[R*64 + ((k0    ) ^ swzR)];
      const float4 f1 = *(const float4*)&hA[R*64 + ((k0 + 4) ^ swzR)];
      f16x8 hi8, lo8;
      float v0;
      v0=f0.x; hi8[0]=(_Float16)v0; lo8[0]=(_Float16)(v0-(float)hi8[0]);
      v0=f0.y; hi8[1]=(_Float16)v0; lo8[1]=(_Float16)(v0-(float)hi8[1]);
      v0=f0.z; hi8[2]=(_Float16)v0; lo8[2]=(_Float16)(v0-(float)hi8[2]);
      v0=f0.w; hi8[3]=(_Float16)v0; lo8[3]=(_Float16)(v0-(float)hi8[3]);
      v0=f1.x; hi8[4]=(_Float16)v0; lo8[4]=(_Float16)(v0-(float)hi8[4]);
      v0=f1.y; hi8[5]=(_Float16)v0; lo8[5]=(_Float16)(v0-(float)hi8[5]);
      v0=f1.z; hi8[6]=(_Float16)v0; lo8[6]=(_Float16)(v0-(float)hi8[6]);
      v0=f1.w; hi8[7]=(_Float16)v0; lo8[7]=(_Float16)(v0-(float)hi8[7]);
      ahi[mt][kb]=hi8; alo[mt][kb]=lo8;
    }
  }

  // GEMM3: p = lrelu(s_new @ p1_w + p1_b); column-sum over rows -> g_psum
  #pragma unroll
  for (int nt=0;nt<8;nt++){
    f16x8 wh0 = g_wp1hi[(nt*2+0)*64 + l], wl0 = g_wp1lo[(nt*2+0)*64 + l];
    f16x8 wh1 = g_wp1hi[(nt*2+1)*64 + l], wl1 = g_wp1lo[(nt*2+1)*64 + l];
    int c = nt*16 + l15;
    float pb = p1_b[c];
    float colacc = 0.f;
    #pragma unroll
    for (int mt=0;mt<2;mt++){
      f32x4 a = {pb, pb, pb, pb};
      a = __builtin_amdgcn_mfma_f32_16x16x32_f16(ahi[mt][0], wh0, a, 0,0,0);
      a = __builtin_amdgcn_mfma_f32_16x16x32_f16(ahi[mt][1], wh1, a, 0,0,0);
      a = __builtin_amdgcn_mfma_f32_16x16x32_f16(ahi[mt][0], wl0, a, 0,0,0);
      a = __builtin_amdgcn_mfma_f32_16x16x32_f16(ahi[mt][1], wl1, a, 0,0,0);
      a = __builtin_amdgcn_mfma_f32_16x16x32_f16(alo[mt][0], wh0, a, 0,0,0);
      a = __builtin_amdgcn_mfma_f32_16x16x32_f16(alo[mt][1], wh1, a, 0,0,0);
      #pragma unroll
      for (int r=0;r<4;r++) colacc += lrelu(a[r]);
    }
    colacc += __shfl_xor(colacc, 16, 64);
    colacc += __shfl_xor(colacc, 32, 64);
    if (lg == 0) atomicAdd(&g_psum[b*NMLP + c], colacc);
  }
}

// ---------------- head: mean over nodes + final linear -----------------------
__global__ void k_head(const float* __restrict__ p2_w, const float* __restrict__ p2_b,
                       float* __restrict__ out) {
  int t = threadIdx.x; // 64 threads: 8 batches x 8 lanes
  int b = t >> 3, l = t & 7;
  float s = 0.f;
  for (int c=l;c<NMLP;c+=8) s += g_psum[b*NMLP + c] * p2_w[c];
  s += __shfl_xor(s, 1, 64);
  s += __shfl_xor(s, 2, 64);
  s += __shfl_xor(s, 4, 64);
  if (l == 0) out[b] = s * (1.f/(float)NNODE) + p2_b[0];
}

extern "C" void kernel_launch(void* const* d_in, const int* in_sizes, int n_in,
                              void* d_out, int out_size, void* d_ws, size_t ws_size,
                              hipStream_t stream) {
  (void)in_sizes; (void)n_in; (void)out_size; (void)d_ws; (void)ws_size;
  const float* sites = (const float*)d_in[0];
  const float* bonds = (const float*)d_in[1];
  const int*   idx1  = (const int*)d_in[2];
  const int*   idx2  = (const int*)d_in[3];
  const int*   uc    = (const int*)d_in[4];
  const float* se_w  = (const float*)d_in[5];
  const float* se_b  = (const float*)d_in[6];
  const float* ee_w  = (const float*)d_in[7];
  const float* ee_b  = (const float*)d_in[8];
  const float* m1a_w = (const float*)d_in[9];
  const float* m1a_b = (const float*)d_in[10];
  const float* m1b_w = (const float*)d_in[11];
  const float* m1b_b = (const float*)d_in[12];
  const float* m2a_w = (const float*)d_in[13];
  const float* m2a_b = (const float*)d_in[14];
  const float* m2b_w = (const float*)d_in[15];
  const float* m2b_b = (const float*)d_in[16];
  const float* att1_w = (const float*)d_in[17];
  const float* att1_b = (const float*)d_in[18];
  const float* att2_w = (const float*)d_in[19];
  const float* att2_b = (const float*)d_in[20];
  const float* nu1_w = (const float*)d_in[21];
  const float* nu1_b = (const float*)d_in[22];
  const float* nu2_w = (const float*)d_in[23];
  const float* nu2_b = (const float*)d_in[24];
  const float* p1_w  = (const float*)d_in[25];
  const float* p1_b  = (const float*)d_in[26];
  const float* p2_w  = (const float*)d_in[27];
  const float* p2_b  = (const float*)d_in[28];

  k_setup<<<2, 1024, 0, stream>>>(uc, idx2, se_w, se_b, ee_w, ee_b,
                                  m1a_w, m1a_b, m2a_w, m2a_b, nu1_w, nu1_b,
                                  m1b_w, m2b_w, nu2_w, p1_w);
  k_edge<<<4100, 128, 0, stream>>>(sites, bonds, idx1, idx2,
                                   m1b_b, m2b_b,
                                   att1_w, att1_b, att2_w, att2_b);
  k_node<<<NB*32, 128, 0, stream>>>(sites, se_w, se_b, nu2_b, p1_b);
  k_head<<<1, 64, 0, stream>>>(p2_w, p2_b, (float*)d_out);
}

// Round 20
// 98.439 us; speedup vs baseline: 2.4274x; 2.4274x over previous
//
#include <hip/hip_runtime.h>

#define NB 8
#define NNODE 2048
#define NE 32768
#define NG 4
#define NH 64
#define NMLP 128

typedef _Float16 f16x8 __attribute__((ext_vector_type(8)));
typedef _Float16 f16x4 __attribute__((ext_vector_type(4)));
typedef float f32x4 __attribute__((ext_vector_type(4)));

// ---------------- persistent device scratch ----------------------------------
__device__ __align__(16) float g_bc[2*NG*64];        // folded layer-1 bias
__device__ __align__(16) float g_q1[64];             // se_w @ nu1_w[0:64]
__device__ __align__(16) float g_b1f[64];            // se_b @ nu1_w[0:64] + nu1_b
__device__ __align__(16) _Float16 g_em16[(size_t)NE*NB*64]; // edge messages, CSR-ordered (fp16)
__device__ __align__(16) float g_msg[NB*NNODE*64];   // per-node reduced messages
__device__ __align__(16) float g_psum[NB*NMLP];
// split-fp16 fragment tables (filled once by k_setup block 1)
__device__ f16x8 g_w1hi[2*NG*4*64];       // edge layer-1 folded W frags [p][g][nt][lane] (K=32)
__device__ f16x8 g_w1lo[2*NG*4*64];
__device__ f16x4 g_w2hi16[2*NG*4*4*64];   // edge layer-2 W frags [p][g][nto][ntk][lane] (K=16)
__device__ f16x4 g_w2lo16[2*NG*4*4*64];
__device__ f16x8 g_wn1hi[4*2*64];         // node nu1_w[64:] frags [nt][kb][lane] (K=32)
__device__ f16x8 g_wn1lo[4*2*64];
__device__ f16x8 g_wn2hi[4*2*64];         // node nu2_w frags
__device__ f16x8 g_wn2lo[4*2*64];
__device__ f16x8 g_wp1hi[8*2*64];         // node p1_w frags [nt8][kb][lane]
__device__ f16x8 g_wp1lo[8*2*64];
__device__ int g_elist[NG*NE];
__device__ int g_ecnt[NG];
__device__ int g_bstart[5];
__device__ int g_ncnt[NNODE];
__device__ int g_noff[NNODE];
__device__ int g_csrpos[NE];              // inverse CSR map: edge -> position

__device__ __forceinline__ float lrelu(float x){ return fmaxf(x, 0.01f*x); }

// ---------------- setup: block 0 = prep (sort/CSR), block 1 = fold+frag ------
__global__ __launch_bounds__(1024) void k_setup(
    const int* __restrict__ uc, const int* __restrict__ idx2,
    const float* __restrict__ se_w, const float* __restrict__ se_b,
    const float* __restrict__ ee_w, const float* __restrict__ ee_b,
    const float* __restrict__ m1a_w, const float* __restrict__ m1a_b,
    const float* __restrict__ m2a_w, const float* __restrict__ m2a_b,
    const float* __restrict__ nu1_w, const float* __restrict__ nu1_b,
    const float* __restrict__ m1b_w, const float* __restrict__ m2b_w,
    const float* __restrict__ nu2_w, const float* __restrict__ p1_w) {
  int t = threadIdx.x;
  if (blockIdx.x == 0) {
    // =================== PREP ===================
    __shared__ unsigned long long sgs[16];
    __shared__ int sws[16];
    __shared__ int sbins[NNODE];
    int lane = t & 63, wv = t >> 6;
    g_psum[t] = 0.f;                      // NB*NMLP == 1024

    int ucr[32], ixr[32];
    #pragma unroll
    for (int j=0;j<32;j++) ucr[j] = uc[j*1024 + t];
    #pragma unroll
    for (int j=0;j<32;j++) ixr[j] = idx2[j*1024 + t];

    // ---- bucket edges by group: packed u64 counts, block scan ----
    unsigned long long cnt = 0;
    #pragma unroll
    for (int j=0;j<32;j++) cnt += 1ULL << (ucr[j]*16);
    unsigned long long inc = cnt;
    #pragma unroll
    for (int d=1; d<64; d<<=1){
      unsigned long long v = __shfl_up(inc, d, 64);
      if (lane >= d) inc += v;
    }
    if (lane == 63) sgs[wv] = inc;
    __syncthreads();
    if (t < 16){
      unsigned long long w = sgs[t];
      #pragma unroll
      for (int d=1; d<16; d<<=1){
        unsigned long long v = __shfl_up(w, d, 64);
        if (t >= d) w += v;
      }
      sgs[t] = w;
    }
    __syncthreads();
    unsigned long long tot  = sgs[15];
    unsigned long long excl = inc - cnt + (wv ? sgs[wv-1] : 0);
    int tg0 = (int)(tot & 0xFFFF),        tg1 = (int)((tot>>16) & 0xFFFF),
        tg2 = (int)((tot>>32) & 0xFFFF),  tg3 = (int)((tot>>48) & 0xFFFF);
    // group-relative positions (g_elist is segmented by g*NE) — r12 fix
    int c0 = (int)(excl & 0xFFFF);
    int c1 = (int)((excl>>16) & 0xFFFF);
    int c2 = (int)((excl>>32) & 0xFFFF);
    int c3 = (int)((excl>>48) & 0xFFFF);
    #pragma unroll
    for (int j=0;j<32;j++){
      int e = j*1024 + t, g = ucr[j], pos;
      if      (g==0) pos = c0++;
      else if (g==1) pos = c1++;
      else if (g==2) pos = c2++;
      else           pos = c3++;
      g_elist[g*NE + pos] = e;
    }
    if (t == 0){
      g_ecnt[0]=tg0; g_ecnt[1]=tg1; g_ecnt[2]=tg2; g_ecnt[3]=tg3;
      int b1 = (tg0+7)/8, b2 = b1+(tg1+7)/8, b3 = b2+(tg2+7)/8, b4 = b3+(tg3+7)/8;
      g_bstart[0]=0; g_bstart[1]=b1; g_bstart[2]=b2; g_bstart[3]=b3; g_bstart[4]=b4;
    }

    // ---- node CSR offsets + inverse map (edge -> position) ----
    sbins[t] = 0; sbins[t+1024] = 0;
    __syncthreads();
    #pragma unroll
    for (int j=0;j<32;j++) atomicAdd(&sbins[ixr[j]], 1);
    __syncthreads();
    int b0v = sbins[2*t], b1v = sbins[2*t+1];
    int s = b0v + b1v;
    int insc = s;
    #pragma unroll
    for (int d=1; d<64; d<<=1){
      int v = __shfl_up(insc, d, 64);
      if (lane >= d) insc += v;
    }
    if (lane == 63) sws[wv] = insc;
    __syncthreads();
    if (t < 16){
      int w = sws[t];
      #pragma unroll
      for (int d=1; d<16; d<<=1){
        int v = __shfl_up(w, d, 64);
        if (t >= d) w += v;
      }
      sws[t] = w;
    }
    __syncthreads();
    int ex = insc - s + (wv ? sws[wv-1] : 0);
    g_ncnt[2*t] = b0v; g_ncnt[2*t+1] = b1v;
    g_noff[2*t] = ex;  g_noff[2*t+1] = ex + b0v;
    __syncthreads();
    sbins[2*t] = ex; sbins[2*t+1] = ex + b0v;
    __syncthreads();
    #pragma unroll
    for (int j=0;j<32;j++){
      int pos = atomicAdd(&sbins[ixr[j]], 1);
      g_csrpos[j*1024 + t] = pos;
    }
  } else {
    // =================== FOLD + FRAGMENT TABLES ===================
    __shared__ float sfold[2*NG*12*64];   // 24 KB
    if (t < 512) {
      int p = t>>8, g = (t>>6)&3, j = t&63;
      const float* ma = (p ? m2a_w : m1a_w) + g*160*64;
      const float* mb = (p ? m2a_b : m1a_b) + g*64;
      float* W = sfold + (p*NG+g)*12*64;
      float a0=0.f, a1=0.f, bc=0.f;
      for (int k=0;k<64;k++){
        float sw = se_w[k], sb = se_b[k];
        float w0 = ma[k*64+j], w1 = ma[(64+k)*64+j];
        a0 += sw*w0; a1 += sw*w1; bc += sb*(w0+w1);
      }
      W[0*64+j]=a0; W[1*64+j]=a1;
      for (int c=0;c<10;c++){
        float pc=0.f;
        for (int u=0;u<32;u++) pc += ee_w[c*32+u]*ma[(128+u)*64+j];
        W[(2+c)*64+j]=pc;
      }
      for (int u=0;u<32;u++) bc += ee_b[u]*ma[(128+u)*64+j];
      g_bc[(p*NG+g)*64+j] = bc + mb[j];
    } else if (t < 576) {
      int j = t - 512;
      float q=0.f, bf=0.f;
      for (int k=0;k<64;k++){ float w = nu1_w[k*64+j]; q += se_w[k]*w; bf += se_b[k]*w; }
      g_q1[j]=q; g_b1f[j]=bf + nu1_b[j];
    }
    __syncthreads();

    for (int i = t; i < 12288; i += 1024) {
      if (i < 8192) {               // edge W2 K16 frags
        int lane = i & 63, ntk = (i>>6)&3, nto = (i>>8)&3, g = (i>>10)&3, p = (i>>12)&1;
        int l15 = lane & 15, lg = lane >> 4;
        const float* W2g = (p ? m2b_w : m1b_w) + g*64*64;
        int n = nto*16 + l15;
        f16x4 h4, l4;
        #pragma unroll
        for (int j=0;j<4;j++){
          float w = W2g[(ntk*16 + lg*4 + j)*64 + n];
          _Float16 hh = (_Float16)w;
          h4[j] = hh; l4[j] = (_Float16)(w - (float)hh);
        }
        g_w2hi16[i] = h4; g_w2lo16[i] = l4;
      } else if (i < 10240) {       // edge W1 K32 frags (2048)
        int k2 = i - 8192;
        int lane = k2 & 63, nt = (k2>>6)&3, g = (k2>>8)&3, p = (k2>>10)&1;
        int l15 = lane & 15, lg = lane >> 4;
        const float* Wf = sfold + (p*NG+g)*12*64;
        int c = nt*16 + l15;
        f16x8 h8, l8;
        #pragma unroll
        for (int j=0;j<8;j++){
          int k = lg*8 + j;
          float w = (k < 12) ? Wf[k*64 + c] : 0.f;
          _Float16 hh = (_Float16)w;
          h8[j] = hh; l8[j] = (_Float16)(w - (float)hh);
        }
        g_w1hi[k2] = h8; g_w1lo[k2] = l8;
      } else if (i < 10752) {       // node nu1_w[64:] frags
        int k2 = i - 10240;
        int lane = k2 & 63, kb = (k2>>6)&1, nt = (k2>>7)&3;
        int l15 = lane & 15, lg = lane >> 4;
        int c = nt*16 + l15;
        f16x8 h8, l8;
        #pragma unroll
        for (int j=0;j<8;j++){
          float w = nu1_w[(64 + kb*32 + lg*8 + j)*64 + c];
          _Float16 hh = (_Float16)w;
          h8[j] = hh; l8[j] = (_Float16)(w - (float)hh);
        }
        g_wn1hi[k2] = h8; g_wn1lo[k2] = l8;
      } else if (i < 11264) {       // node nu2_w frags
        int k2 = i - 10752;
        int lane = k2 & 63, kb = (k2>>6)&1, nt = (k2>>7)&3;
        int l15 = lane & 15, lg = lane >> 4;
        int c = nt*16 + l15;
        f16x8 h8, l8;
        #pragma unroll
        for (int j=0;j<8;j++){
          float w = nu2_w[(kb*32 + lg*8 + j)*64 + c];
          _Float16 hh = (_Float16)w;
          h8[j] = hh; l8[j] = (_Float16)(w - (float)hh);
        }
        g_wn2hi[k2] = h8; g_wn2lo[k2] = l8;
      } else {                      // node p1_w frags (8 nt)
        int k2 = i - 11264;
        int lane = k2 & 63, kb = (k2>>6)&1, nt = (k2>>7)&7;
        int l15 = lane & 15, lg = lane >> 4;
        int c = nt*16 + l15;
        f16x8 h8, l8;
        #pragma unroll
        for (int j=0;j<8;j++){
          float w = p1_w[(kb*32 + lg*8 + j)*128 + c];
          _Float16 hh = (_Float16)w;
          h8[j] = hh; l8[j] = (_Float16)(w - (float)hh);
        }
        g_wp1hi[k2] = h8; g_wp1lo[k2] = l8;
      }
    }
  }
}

// ---------------- edge kernel: 8 edges x 8 batches = 64 rows per block -------
// r16 configuration (measured best ~45us): fp16-hi activations, weight hi/lo
// kept, JIT W2 loads, direct CSR-ordered scatter store.
__global__ __launch_bounds__(128) void k_edge(
    const float* __restrict__ sites, const float* __restrict__ bonds,
    const int* __restrict__ idx1, const int* __restrict__ idx2,
    const float* __restrict__ m1b_b, const float* __restrict__ m2b_b,
    const float* __restrict__ att1_w, const float* __restrict__ att1_b,
    const float* __restrict__ att2_w, const float* __restrict__ att2_b) {
  int bid = blockIdx.x;
  if (bid >= g_bstart[4]) return;
  int g;
  if      (bid < g_bstart[1]) g = 0;
  else if (bid < g_bstart[2]) g = 1;
  else if (bid < g_bstart[3]) g = 2;
  else                        g = 3;
  int cnt = g_ecnt[g];
  int e8 = (bid - g_bstart[g]) * 8;

  __shared__ __align__(16) float fls[64*12];
  __shared__ int sidx[64];

  int t = threadIdx.x;
  int l = t & 63;
  int wv = t >> 6;
  int l15 = l & 15;
  int lg  = l >> 4;

  if (t < 64) {
    int r = t, ei = r>>3, b = r&7;
    int eslot = e8 + ei;
    bool valid = eslot < cnt;
    int e = g_elist[g*NE + (valid ? eslot : e8)];
    int i1 = idx1[e], i2 = idx2[e];
    float d = bonds[b*NE + e];
    fls[r*12+0] = sites[b*NNODE + i1];
    fls[r*12+1] = sites[b*NNODE + i2];
    sidx[r] = valid ? (g_csrpos[e]*NB + b)*64 : -1;   // CSR-ordered destination
    #pragma unroll
    for (int c=0;c<10;c++){
      float dd = d - c*(10.f/9.f);
      fls[r*12+2+c] = __expf(-dd*dd);
    }
  }
  __syncthreads();

  // feature fragments (MFMA B operand), fp16-hi only: col r=l15, k=lg*8+jj
  f16x8 fhi[2];
  #pragma unroll
  for (int mt=0;mt<2;mt++){
    f16x8 h8;
    #pragma unroll
    for (int j=0;j<8;j++) h8[j]=(_Float16)0;
    int R = wv*32 + mt*16 + l15;
    if (lg == 0){
      float4 f0 = *(const float4*)&fls[R*12];
      float4 f1 = *(const float4*)&fls[R*12+4];
      h8[0]=(_Float16)f0.x; h8[1]=(_Float16)f0.y;
      h8[2]=(_Float16)f0.z; h8[3]=(_Float16)f0.w;
      h8[4]=(_Float16)f1.x; h8[5]=(_Float16)f1.y;
      h8[6]=(_Float16)f1.z; h8[7]=(_Float16)f1.w;
    } else if (lg == 1){
      float4 f2 = *(const float4*)&fls[R*12+8];
      h8[0]=(_Float16)f2.x; h8[1]=(_Float16)f2.y;
      h8[2]=(_Float16)f2.z; h8[3]=(_Float16)f2.w;
    }
    fhi[mt]=h8;
  }

  float comb[2][4][4];
  #pragma unroll
  for (int mt=0;mt<2;mt++)
    #pragma unroll
    for (int nt=0;nt<4;nt++)
      #pragma unroll
      for (int r=0;r<4;r++) comb[mt][nt][r] = 0.f;

  #pragma unroll
  for (int p=0;p<2;p++){
    const float* b2g = (p ? m2b_b : m1b_b) + g*64;
    int pg = p*NG + g;

    // ---- layer 1: C1 = mfma(W1, feat) = h^T — lands in K=16 A-frag layout
    f16x4 ah[4][2];   // [ntk][mt]
    #pragma unroll
    for (int nt=0;nt<4;nt++){
      int b1 = (pg*4 + nt)*64 + l;
      f16x8 w1h = g_w1hi[b1], w1l = g_w1lo[b1];
      float4 bc4 = *(const float4*)&g_bc[pg*64 + nt*16 + lg*4];
      #pragma unroll
      for (int mt=0;mt<2;mt++){
        f32x4 a = {bc4.x, bc4.y, bc4.z, bc4.w};
        a = __builtin_amdgcn_mfma_f32_16x16x32_f16(w1h, fhi[mt], a, 0,0,0);
        a = __builtin_amdgcn_mfma_f32_16x16x32_f16(w1l, fhi[mt], a, 0,0,0);
        f16x4 h4;
        #pragma unroll
        for (int r=0;r<4;r++) h4[r] = (_Float16)lrelu(a[r]);
        ah[nt][mt] = h4;
      }
    }

    // ---- layer 2: out[mt][nto] via K=16 MFMA over 4 ntk tiles
    f32x4 accp[2][4];
    #pragma unroll
    for (int nto=0;nto<4;nto++){
      float bias = b2g[nto*16 + l15];
      f32x4 a0v = {bias, bias, bias, bias};
      f32x4 a1v = {bias, bias, bias, bias};
      #pragma unroll
      for (int ntk=0;ntk<4;ntk++){
        int bi = (((pg*4 + nto)*4) + ntk)*64 + l;
        f16x4 bh = g_w2hi16[bi], bl = g_w2lo16[bi];
        a0v = __builtin_amdgcn_mfma_f32_16x16x16f16(ah[ntk][0], bh, a0v, 0,0,0);
        a0v = __builtin_amdgcn_mfma_f32_16x16x16f16(ah[ntk][0], bl, a0v, 0,0,0);
        a1v = __builtin_amdgcn_mfma_f32_16x16x16f16(ah[ntk][1], bh, a1v, 0,0,0);
        a1v = __builtin_amdgcn_mfma_f32_16x16x16f16(ah[ntk][1], bl, a1v, 0,0,0);
      }
      accp[0][nto] = a0v; accp[1][nto] = a1v;
    }

    // ---- per-path epilogue: leaky -> attention gate -> accumulate into comb
    float ab = p ? att2_b[0] : att1_b[0];
    const float* aw = p ? att2_w : att1_w;
    #pragma unroll
    for (int mt=0;mt<2;mt++){
      float o[4][4];
      float pa[4] = {0.f,0.f,0.f,0.f};
      #pragma unroll
      for (int nt=0;nt<4;nt++){
        float w = aw[nt*16 + l15];
        #pragma unroll
        for (int r=0;r<4;r++){
          float ov = lrelu(accp[mt][nt][r]);
          o[nt][r] = ov;
          pa[r] += ov * w;
        }
      }
      #pragma unroll
      for (int r=0;r<4;r++){
        float s = pa[r];
        s += __shfl_xor(s, 1, 64);
        s += __shfl_xor(s, 2, 64);
        s += __shfl_xor(s, 4, 64);
        s += __shfl_xor(s, 8, 64);
        float sg = 1.f/(1.f + __expf(-(s + ab)));
        #pragma unroll
        for (int nt=0;nt<4;nt++) comb[mt][nt][r] += sg * o[nt][r];
      }
    }
  }

  // store combined messages as fp16 (CSR-ordered rows)
  #pragma unroll
  for (int mt=0;mt<2;mt++){
    #pragma unroll
    for (int r=0;r<4;r++){
      int R = wv*32 + mt*16 + lg*4 + r;
      int sb = sidx[R];
      if (sb >= 0){
        #pragma unroll
        for (int nt=0;nt<4;nt++) g_em16[sb + nt*16 + l15] = (_Float16)comb[mt][nt][r];
      }
    }
  }
}

// ---------------- gather: sequential CSR segment-reduce (fp16), no indirection
__global__ __launch_bounds__(256) void k_gather() {
  int w = blockIdx.x*4 + (threadIdx.x >> 6);
  int lane = threadIdx.x & 63;
  int n = w >> 3, b = w & 7;
  int off = g_noff[n], deg = g_ncnt[n];
  float s0 = 0.f, s1 = 0.f;
  int i = 0;
  for (; i+2 <= deg; i += 2){
    s0 += (float)g_em16[(size_t)((off+i  )*NB + b)*64 + lane];
    s1 += (float)g_em16[(size_t)((off+i+1)*NB + b)*64 + lane];
  }
  if (i < deg){
    s0 += (float)g_em16[(size_t)((off+i)*NB + b)*64 + lane];
  }
  g_msg[(b*NNODE + n)*64 + lane] = s0 + s1;
}

// ---------------- node kernel: 64 nodes/block, 3 chained MFMA GEMMs ----------
__global__ __launch_bounds__(128) void k_node(
    const float* __restrict__ sites,
    const float* __restrict__ se_w, const float* __restrict__ se_b,
    const float* __restrict__ nu2_b, const float* __restrict__ p1_b) {
  __shared__ __align__(16) float hA[64*64];
  __shared__ float xs[64];
  int t = threadIdx.x;
  int l = t & 63;
  int wv = t >> 6;
  int l15 = l & 15;
  int lg  = l >> 4;
  int swzR = l15 << 2;
  int b = blockIdx.x >> 5;
  int nbase = (blockIdx.x & 31) * 64;
  int wb = wv*32;

  if (t < 64) xs[t] = sites[b*NNODE + nbase + t];
  __syncthreads();

  // GEMM1 A-frags straight from g_msg: row=l15, k=kb*32+lg*8+j
  f16x8 ahi[2][2], alo[2][2];
  #pragma unroll
  for (int mt=0;mt<2;mt++){
    int row = b*NNODE + nbase + wb + mt*16 + l15;
    #pragma unroll
    for (int kb=0;kb<2;kb++){
      int k0 = kb*32 + lg*8;
      const float4 f0 = *(const float4*)&g_msg[row*64 + k0];
      const float4 f1 = *(const float4*)&g_msg[row*64 + k0 + 4];
      f16x8 hi8, lo8;
      float v0;
      v0=f0.x; hi8[0]=(_Float16)v0; lo8[0]=(_Float16)(v0-(float)hi8[0]);
      v0=f0.y; hi8[1]=(_Float16)v0; lo8[1]=(_Float16)(v0-(float)hi8[1]);
      v0=f0.z; hi8[2]=(_Float16)v0; lo8[2]=(_Float16)(v0-(float)hi8[2]);
      v0=f0.w; hi8[3]=(_Float16)v0; lo8[3]=(_Float16)(v0-(float)hi8[3]);
      v0=f1.x; hi8[4]=(_Float16)v0; lo8[4]=(_Float16)(v0-(float)hi8[4]);
      v0=f1.y; hi8[5]=(_Float16)v0; lo8[5]=(_Float16)(v0-(float)hi8[5]);
      v0=f1.z; hi8[6]=(_Float16)v0; lo8[6]=(_Float16)(v0-(float)hi8[6]);
      v0=f1.w; hi8[7]=(_Float16)v0; lo8[7]=(_Float16)(v0-(float)hi8[7]);
      ahi[mt][kb]=hi8; alo[mt][kb]=lo8;
    }
  }

  // GEMM1: h1 = lrelu(x*q1 + msg @ nu1_w[64:] + b1f) -> swizzled LDS
  #pragma unroll
  for (int nt=0;nt<4;nt++){
    f16x8 wh0 = g_wn1hi[(nt*2+0)*64 + l], wl0 = g_wn1lo[(nt*2+0)*64 + l];
    f16x8 wh1 = g_wn1hi[(nt*2+1)*64 + l], wl1 = g_wn1lo[(nt*2+1)*64 + l];
    int c = nt*16 + l15;
    float q = g_q1[c], bf = g_b1f[c];
    #pragma unroll
    for (int mt=0;mt<2;mt++){
      f32x4 a;
      #pragma unroll
      for (int r=0;r<4;r++){ int R = wb + mt*16 + lg*4 + r; a[r] = xs[R]*q + bf; }
      a = __builtin_amdgcn_mfma_f32_16x16x32_f16(ahi[mt][0], wh0, a, 0,0,0);
      a = __builtin_amdgcn_mfma_f32_16x16x32_f16(ahi[mt][1], wh1, a, 0,0,0);
      a = __builtin_amdgcn_mfma_f32_16x16x32_f16(ahi[mt][0], wl0, a, 0,0,0);
      a = __builtin_amdgcn_mfma_f32_16x16x32_f16(ahi[mt][1], wl1, a, 0,0,0);
      a = __builtin_amdgcn_mfma_f32_16x16x32_f16(alo[mt][0], wh0, a, 0,0,0);
      a = __builtin_amdgcn_mfma_f32_16x16x32_f16(alo[mt][1], wh1, a, 0,0,0);
      #pragma unroll
      for (int r=0;r<4;r++){
        int R = wb + mt*16 + lg*4 + r;
        hA[R*64 + (c ^ ((R&15)<<2))] = lrelu(a[r]);
      }
    }
  }

  // read h1 back (wave-private)
  #pragma unroll
  for (int mt=0;mt<2;mt++){
    int R = wb + mt*16 + l15;
    #pragma unroll
    for (int kb=0;kb<2;kb++){
      int k0 = kb*32 + lg*8;
      const float4 f0 = *(const float4*)&hA[R*64 + ((k0    ) ^ swzR)];
      const float4 f1 = *(const float4*)&hA[R*64 + ((k0 + 4) ^ swzR)];
      f16x8 hi8, lo8;
      float v0;
      v0=f0.x; hi8[0]=(_Float16)v0; lo8[0]=(_Float16)(v0-(float)hi8[0]);
      v0=f0.y; hi8[1]=(_Float16)v0; lo8[1]=(_Float16)(v0-(float)hi8[1]);
      v0=f0.z; hi8[2]=(_Float16)v0; lo8[2]=(_Float16)(v0-(float)hi8[2]);
      v0=f0.w; hi8[3]=(_Float16)v0; lo8[3]=(_Float16)(v0-(float)hi8[3]);
      v0=f1.x; hi8[4]=(_Float16)v0; lo8[4]=(_Float16)(v0-(float)hi8[4]);
      v0=f1.y; hi8[5]=(_Float16)v0; lo8[5]=(_Float16)(v0-(float)hi8[5]);
      v0=f1.z; hi8[6]=(_Float16)v0; lo8[6]=(_Float16)(v0-(float)hi8[6]);
      v0=f1.w; hi8[7]=(_Float16)v0; lo8[7]=(_Float16)(v0-(float)hi8[7]);
      ahi[mt][kb]=hi8; alo[mt][kb]=lo8;
    }
  }

  // GEMM2: s_new = x*se_w + se_b + lrelu(h1 @ nu2_w + nu2_b) -> swizzled LDS
  #pragma unroll
  for (int nt=0;nt<4;nt++){
    f16x8 wh0 = g_wn2hi[(nt*2+0)*64 + l], wl0 = g_wn2lo[(nt*2+0)*64 + l];
    f16x8 wh1 = g_wn2hi[(nt*2+1)*64 + l], wl1 = g_wn2lo[(nt*2+1)*64 + l];
    int c = nt*16 + l15;
    float b2 = nu2_b[c], sw = se_w[c], sb2 = se_b[c];
    #pragma unroll
    for (int mt=0;mt<2;mt++){
      f32x4 a = {b2, b2, b2, b2};
      a = __builtin_amdgcn_mfma_f32_16x16x32_f16(ahi[mt][0], wh0, a, 0,0,0);
      a = __builtin_amdgcn_mfma_f32_16x16x32_f16(ahi[mt][1], wh1, a, 0,0,0);
      a = __builtin_amdgcn_mfma_f32_16x16x32_f16(ahi[mt][0], wl0, a, 0,0,0);
      a = __builtin_amdgcn_mfma_f32_16x16x32_f16(ahi[mt][1], wl1, a, 0,0,0);
      a = __builtin_amdgcn_mfma_f32_16x16x32_f16(alo[mt][0], wh0, a, 0,0,0);
      a = __builtin_amdgcn_mfma_f32_16x16x32_f16(alo[mt][1], wh1, a, 0,0,0);
      #pragma unroll
      for (int r=0;r<4;r++){
        int R = wb + mt*16 + lg*4 + r;
        hA[R*64 + (c ^ ((R&15)<<2))] = xs[R]*sw + sb2 + lrelu(a[r]);
      }
    }
  }

  // read s_new back (wave-private)
  #pragma unroll
  for (int mt=0;mt<2;mt++){
    int R = wb + mt*16 + l15;
    #pragma unroll
    for (int kb=0;kb<2;kb++){
      int k0 = kb*32 + lg*8;
      const float4 f0 = *(const float4*)&hA[R*64 + ((k0    ) ^ swzR)];
      const float4 f1 = *(const float4*)&hA[R*64 + ((k0 + 4) ^ swzR)];
      f16x8 hi8, lo8;
      float v0;
      v0=f0.x; hi8[0]=(_Float16)v0; lo8[0]=(_Float16)(v0-(float)hi8[0]);
      v0=f0.y; hi8[1]=(_Float16)v0; lo8[1]=(_Float16)(v0-(float)hi8[1]);
      v0=f0.z; hi8[2]=(_Float16)v0; lo8[2]=(_Float16)(v0-(float)hi8[2]);
      v0=f0.w; hi8[3]=(_Float16)v0; lo8[3]=(_Float16)(v0-(float)hi8[3]);
      v0=f1.x; hi8[4]=(_Float16)v0; lo8[4]=(_Float16)(v0-(float)hi8[4]);
      v0=f1.y; hi8[5]=(_Float16)v0; lo8[5]=(_Float16)(v0-(float)hi8[5]);
      v0=f1.z; hi8[6]=(_Float16)v0; lo8[6]=(_Float16)(v0-(float)hi8[6]);
      v0=f1.w; hi8[7]=(_Float16)v0; lo8[7]=(_Float16)(v0-(float)hi8[7]);
      ahi[mt][kb]=hi8; alo[mt][kb]=lo8;
    }
  }

  // GEMM3: p = lrelu(s_new @ p1_w + p1_b); column-sum over rows -> g_psum
  #pragma unroll
  for (int nt=0;nt<8;nt++){
    f16x8 wh0 = g_wp1hi[(nt*2+0)*64 + l], wl0 = g_wp1lo[(nt*2+0)*64 + l];
    f16x8 wh1 = g_wp1hi[(nt*2+1)*64 + l], wl1 = g_wp1lo[(nt*2+1)*64 + l];
    int c = nt*16 + l15;
    float pb = p1_b[c];
    float colacc = 0.f;
    #pragma unroll
    for (int mt=0;mt<2;mt++){
      f32x4 a = {pb, pb, pb, pb};
      a = __builtin_amdgcn_mfma_f32_16x16x32_f16(ahi[mt][0], wh0, a, 0,0,0);
      a = __builtin_amdgcn_mfma_f32_16x16x32_f16(ahi[mt][1], wh1, a, 0,0,0);
      a = __builtin_amdgcn_mfma_f32_16x16x32_f16(ahi[mt][0], wl0, a, 0,0,0);
      a = __builtin_amdgcn_mfma_f32_16x16x32_f16(ahi[mt][1], wl1, a, 0,0,0);
      a = __builtin_amdgcn_mfma_f32_16x16x32_f16(alo[mt][0], wh0, a, 0,0,0);
      a = __builtin_amdgcn_mfma_f32_16x16x32_f16(alo[mt][1], wh1, a, 0,0,0);
      #pragma unroll
      for (int r=0;r<4;r++) colacc += lrelu(a[r]);
    }
    colacc += __shfl_xor(colacc, 16, 64);
    colacc += __shfl_xor(colacc, 32, 64);
    if (lg == 0) atomicAdd(&g_psum[b*NMLP + c], colacc);
  }
}

// ---------------- head: mean over nodes + final linear -----------------------
__global__ void k_head(const float* __restrict__ p2_w, const float* __restrict__ p2_b,
                       float* __restrict__ out) {
  int t = threadIdx.x; // 64 threads: 8 batches x 8 lanes
  int b = t >> 3, l = t & 7;
  float s = 0.f;
  for (int c=l;c<NMLP;c+=8) s += g_psum[b*NMLP + c] * p2_w[c];
  s += __shfl_xor(s, 1, 64);
  s += __shfl_xor(s, 2, 64);
  s += __shfl_xor(s, 4, 64);
  if (l == 0) out[b] = s * (1.f/(float)NNODE) + p2_b[0];
}

extern "C" void kernel_launch(void* const* d_in, const int* in_sizes, int n_in,
                              void* d_out, int out_size, void* d_ws, size_t ws_size,
                              hipStream_t stream) {
  (void)in_sizes; (void)n_in; (void)out_size; (void)d_ws; (void)ws_size;
  const float* sites = (const float*)d_in[0];
  const float* bonds = (const float*)d_in[1];
  const int*   idx1  = (const int*)d_in[2];
  const int*   idx2  = (const int*)d_in[3];
  const int*   uc    = (const int*)d_in[4];
  const float* se_w  = (const float*)d_in[5];
  const float* se_b  = (const float*)d_in[6];
  const float* ee_w  = (const float*)d_in[7];
  const float* ee_b  = (const float*)d_in[8];
  const float* m1a_w = (const float*)d_in[9];
  const float* m1a_b = (const float*)d_in[10];
  const float* m1b_w = (const float*)d_in[11];
  const float* m1b_b = (const float*)d_in[12];
  const float* m2a_w = (const float*)d_in[13];
  const float* m2a_b = (const float*)d_in[14];
  const float* m2b_w = (const float*)d_in[15];
  const float* m2b_b = (const float*)d_in[16];
  const float* att1_w = (const float*)d_in[17];
  const float* att1_b = (const float*)d_in[18];
  const float* att2_w = (const float*)d_in[19];
  const float* att2_b = (const float*)d_in[20];
  const float* nu1_w = (const float*)d_in[21];
  const float* nu1_b = (const float*)d_in[22];
  const float* nu2_w = (const float*)d_in[23];
  const float* nu2_b = (const float*)d_in[24];
  const float* p1_w  = (const float*)d_in[25];
  const float* p1_b  = (const float*)d_in[26];
  const float* p2_w  = (const float*)d_in[27];
  const float* p2_b  = (const float*)d_in[28];

  k_setup<<<2, 1024, 0, stream>>>(uc, idx2, se_w, se_b, ee_w, ee_b,
                                  m1a_w, m1a_b, m2a_w, m2a_b, nu1_w, nu1_b,
                                  m1b_w, m2b_w, nu2_w, p1_w);
  k_edge<<<4100, 128, 0, stream>>>(sites, bonds, idx1, idx2,
                                   m1b_b, m2b_b,
                                   att1_w, att1_b, att2_w, att2_b);
  k_gather<<<(NNODE*NB)/4, 256, 0, stream>>>();
  k_node<<<NB*32, 128, 0, stream>>>(sites, se_w, se_b, nu2_b, p1_b);
  k_head<<<1, 64, 0, stream>>>(p2_w, p2_b, (float*)d_out);
}